// Round 1
// baseline (211.425 us; speedup 1.0000x reference)
//
#include <hip/hip_runtime.h>
#include <stdint.h>

// Problem dims (fixed by the reference)
#define GM 4096   // 2*2048 rows of x
#define GN 8192   // out_features
#define GK 2048   // in_features

typedef float f32x4 __attribute__((ext_vector_type(4)));
typedef __bf16 bf16x8 __attribute__((ext_vector_type(8)));

__device__ __constant__ float NF4_LUT[16] = {
    -1.0f, -0.6961928009986877f, -0.5250730514526367f, -0.39491748809814453f,
    -0.28444138169288635f, -0.18477343022823334f, -0.09105003625154495f, 0.0f,
    0.07958029955625534f, 0.16093020141124725f, 0.24611230194568634f,
    0.33791524171829224f, 0.44070982933044434f, 0.5626170039176941f,
    0.7229568362236023f, 1.0f};

__device__ __forceinline__ unsigned short f32_to_bf16_rne(float f) {
  union { float f; uint32_t u; } v;
  v.f = f;
  uint32_t lsb = (v.u >> 16) & 1u;
  v.u += 0x7fffu + lsb;
  return (unsigned short)(v.u >> 16);
}

// ---------------- Pass 1: NF4 dequant -> bf16 W [GN][GK] ----------------
// one thread = 8 consecutive elements (all in same 64-elem scale block)
__global__ void __launch_bounds__(256) dequant_nf4_kernel(
    const int* __restrict__ q, const float* __restrict__ scale,
    unsigned short* __restrict__ w) {
  __shared__ float lut[16];
  if (threadIdx.x < 16) lut[threadIdx.x] = NF4_LUT[threadIdx.x];
  __syncthreads();
  int t = blockIdx.x * 256 + threadIdx.x;
  const int4* q4 = reinterpret_cast<const int4*>(q);
  int4 c0 = q4[2 * t];
  int4 c1 = q4[2 * t + 1];
  float s = scale[t >> 3];  // (t*8)/64
  int codes[8] = {c0.x, c0.y, c0.z, c0.w, c1.x, c1.y, c1.z, c1.w};
  union { unsigned short u[8]; int4 v; } r;
#pragma unroll
  for (int j = 0; j < 8; ++j)
    r.u[j] = f32_to_bf16_rne(lut[codes[j] & 15] * s);
  reinterpret_cast<int4*>(w)[t] = r.v;
}

// ---------------- Pass 2: x fp32 -> bf16 [GM][GK] ----------------
__global__ void __launch_bounds__(256) cvt_f32_bf16_kernel(
    const float* __restrict__ x, unsigned short* __restrict__ xb) {
  int t = blockIdx.x * 256 + threadIdx.x;
  const float4* x4 = reinterpret_cast<const float4*>(x);
  float4 a = x4[2 * t];
  float4 b = x4[2 * t + 1];
  union { unsigned short u[8]; int4 v; } r;
  r.u[0] = f32_to_bf16_rne(a.x); r.u[1] = f32_to_bf16_rne(a.y);
  r.u[2] = f32_to_bf16_rne(a.z); r.u[3] = f32_to_bf16_rne(a.w);
  r.u[4] = f32_to_bf16_rne(b.x); r.u[5] = f32_to_bf16_rne(b.y);
  r.u[6] = f32_to_bf16_rne(b.z); r.u[7] = f32_to_bf16_rne(b.w);
  reinterpret_cast<int4*>(xb)[t] = r.v;
}

// ---------------- Pass 3: bf16 GEMM (m97 structure) + bias ----------------
// C[M][N] = A[M][K] * B[N][K]^T + bias ; 128x128 tile, BK=32, 4 waves (2x2),
// each wave 64x64 = 4x4 fragments of 16x16x32 MFMA. global_load_lds width-16.
#define AS1(p) ((const __attribute__((address_space(1))) void*)(p))
#define AS3(p) ((__attribute__((address_space(3))) void*)(p))

__global__ void __launch_bounds__(256) gemm_bf16_bias_kernel(
    const unsigned short* __restrict__ A,  // [GM][GK] bf16 bits
    const unsigned short* __restrict__ B,  // [GN][GK] bf16 bits
    const float* __restrict__ bias, float* __restrict__ C) {
  constexpr int BM = 128, BN = 128, BK = 32;
  __shared__ __align__(16) unsigned short As[BM * BK];  // 8 KB
  __shared__ __align__(16) unsigned short Bs[BN * BK];  // 8 KB

  // XCD-aware swizzle: nwg = 2048, divisible by 8 -> simple form is bijective
  int nwg = gridDim.x;
  int bid = blockIdx.x;
  int cpx = nwg >> 3;
  int swz = (bid & 7) * cpx + (bid >> 3);
  constexpr int TN = GN / BN;  // 64 tiles along N
  int brow = (swz / TN) * BM;
  int bcol = (swz % TN) * BN;

  int t = threadIdx.x;
  int lane = t & 63;
  int wave = t >> 6;

  // Staging: tile is 128x32 bf16 = 8 KB = 512 x 16B chunks; 256 threads x 2.
  // chunk c covers row c/4, cols (c%4)*8..+8. LDS dest = wave-uniform + lane*16.
  int c0 = t, c1 = t + 256;
  int ar0 = c0 >> 2, ac0 = (c0 & 3) * 8;
  int ar1 = c1 >> 2, ac1 = (c1 & 3) * 8;
  const unsigned short* Ab0 = A + (size_t)(brow + ar0) * GK + ac0;
  const unsigned short* Ab1 = A + (size_t)(brow + ar1) * GK + ac1;
  const unsigned short* Bb0 = B + (size_t)(bcol + ar0) * GK + ac0;
  const unsigned short* Bb1 = B + (size_t)(bcol + ar1) * GK + ac1;

  int wr = (wave >> 1) * 64;   // wave's M offset in tile
  int wc = (wave & 1) * 64;    // wave's N offset in tile
  int fr = lane & 15;          // fragment row (A) / col (B)
  int k0 = (lane >> 4) * 8;    // fragment k base

  f32x4 acc[4][4] = {};

  for (int kt = 0; kt < GK; kt += BK) {
    __builtin_amdgcn_global_load_lds(AS1(Ab0 + kt), AS3(&As[c0 * 8]), 16, 0, 0);
    __builtin_amdgcn_global_load_lds(AS1(Ab1 + kt), AS3(&As[c1 * 8]), 16, 0, 0);
    __builtin_amdgcn_global_load_lds(AS1(Bb0 + kt), AS3(&Bs[c0 * 8]), 16, 0, 0);
    __builtin_amdgcn_global_load_lds(AS1(Bb1 + kt), AS3(&Bs[c1 * 8]), 16, 0, 0);
    __syncthreads();  // drains vmcnt(0): staged data visible

    bf16x8 af[4], bfv[4];
#pragma unroll
    for (int mi = 0; mi < 4; ++mi)
      af[mi] = *reinterpret_cast<const bf16x8*>(&As[(wr + mi * 16 + fr) * BK + k0]);
#pragma unroll
    for (int ni = 0; ni < 4; ++ni)
      bfv[ni] = *reinterpret_cast<const bf16x8*>(&Bs[(wc + ni * 16 + fr) * BK + k0]);
#pragma unroll
    for (int mi = 0; mi < 4; ++mi)
#pragma unroll
      for (int ni = 0; ni < 4; ++ni)
        acc[mi][ni] = __builtin_amdgcn_mfma_f32_16x16x32_bf16(
            af[mi], bfv[ni], acc[mi][ni], 0, 0, 0);
    __syncthreads();  // protect LDS before next stage
  }

  // Epilogue: C/D layout = col (lane&15), row (lane>>4)*4 + reg  [m89/m91]
  int row4 = (lane >> 4) * 4;
#pragma unroll
  for (int ni = 0; ni < 4; ++ni) {
    int col = bcol + wc + ni * 16 + fr;
    float bv = bias[col];
#pragma unroll
    for (int mi = 0; mi < 4; ++mi) {
      int rbase = brow + wr + mi * 16 + row4;
#pragma unroll
      for (int r = 0; r < 4; ++r)
        C[(size_t)(rbase + r) * GN + col] = acc[mi][ni][r] + bv;
    }
  }
}

// ---------------- Fallback (ws too small): fp32, correct, slow ----------------
__global__ void __launch_bounds__(256) fallback_kernel(
    const float* __restrict__ x, const int* __restrict__ q,
    const float* __restrict__ scale, const float* __restrict__ bias,
    float* __restrict__ out) {
  __shared__ float wrow[GK];  // one dequantized W row (8 KB)
  int n = blockIdx.x;
  for (int k = threadIdx.x; k < GK; k += 256) {
    size_t idx = (size_t)n * GK + k;
    wrow[k] = NF4_LUT[q[idx] & 15] * scale[idx >> 6];
  }
  __syncthreads();
  int m = blockIdx.y * 256 + threadIdx.x;
  const float* xr = x + (size_t)m * GK;
  float acc = 0.f;
  for (int k = 0; k < GK; ++k) acc += xr[k] * wrow[k];
  out[(size_t)m * GN + n] = acc + bias[n];
}

extern "C" void kernel_launch(void* const* d_in, const int* in_sizes, int n_in,
                              void* d_out, int out_size, void* d_ws, size_t ws_size,
                              hipStream_t stream) {
  const float* x = (const float*)d_in[0];
  const int* q = (const int*)d_in[1];
  const float* scale = (const float*)d_in[2];
  const float* bias = (const float*)d_in[3];
  float* out = (float*)d_out;

  const size_t wbytes = (size_t)GN * GK * 2;  // 33,554,432
  const size_t xbytes = (size_t)GM * GK * 2;  // 16,777,216

  if (ws_size >= wbytes + xbytes) {
    unsigned short* wq = (unsigned short*)d_ws;
    unsigned short* xb = (unsigned short*)((char*)d_ws + wbytes);
    dequant_nf4_kernel<<<(GN * GK / 8) / 256, 256, 0, stream>>>(q, scale, wq);
    cvt_f32_bf16_kernel<<<(GM * GK / 8) / 256, 256, 0, stream>>>(x, xb);
    gemm_bf16_bias_kernel<<<dim3((GM / 128) * (GN / 128)), 256, 0, stream>>>(
        xb, wq, bias, out);
  } else {
    fallback_kernel<<<dim3(GN, GM / 256), 256, 0, stream>>>(x, q, scale, bias, out);
  }
}

// Round 2
// 167.727 us; speedup vs baseline: 1.2605x; 1.2605x over previous
//
#include <hip/hip_runtime.h>
#include <stdint.h>

#define GM 4096   // 2*2048 rows of x
#define GN 8192   // out_features
#define GK 2048   // in_features

typedef float f32x4 __attribute__((ext_vector_type(4)));
typedef __bf16 bf16x8 __attribute__((ext_vector_type(8)));

__device__ __constant__ float NF4_LUT[16] = {
    -1.0f, -0.6961928009986877f, -0.5250730514526367f, -0.39491748809814453f,
    -0.28444138169288635f, -0.18477343022823334f, -0.09105003625154495f, 0.0f,
    0.07958029955625534f, 0.16093020141124725f, 0.24611230194568634f,
    0.33791524171829224f, 0.44070982933044434f, 0.5626170039176941f,
    0.7229568362236023f, 1.0f};

__device__ __forceinline__ unsigned short f32_to_bf16_rne(float f) {
  union { float f; uint32_t u; } v;
  v.f = f;
  uint32_t lsb = (v.u >> 16) & 1u;
  v.u += 0x7fffu + lsb;
  return (unsigned short)(v.u >> 16);
}

// ---------------- Pass 1: NF4 dequant -> bf16 W [GN][GK] ----------------
__global__ void __launch_bounds__(256) dequant_nf4_kernel(
    const int* __restrict__ q, const float* __restrict__ scale,
    unsigned short* __restrict__ w) {
  __shared__ float lut[16];
  if (threadIdx.x < 16) lut[threadIdx.x] = NF4_LUT[threadIdx.x];
  __syncthreads();
  int t = blockIdx.x * 256 + threadIdx.x;
  const int4* q4 = reinterpret_cast<const int4*>(q);
  int4 c0 = q4[2 * t];
  int4 c1 = q4[2 * t + 1];
  float s = scale[t >> 3];
  int codes[8] = {c0.x, c0.y, c0.z, c0.w, c1.x, c1.y, c1.z, c1.w};
  union { unsigned short u[8]; int4 v; } r;
#pragma unroll
  for (int j = 0; j < 8; ++j)
    r.u[j] = f32_to_bf16_rne(lut[codes[j] & 15] * s);
  reinterpret_cast<int4*>(w)[t] = r.v;
}

// ---------------- Pass 2: x fp32 -> bf16 [GM][GK] ----------------
__global__ void __launch_bounds__(256) cvt_f32_bf16_kernel(
    const float* __restrict__ x, unsigned short* __restrict__ xb) {
  int t = blockIdx.x * 256 + threadIdx.x;
  const float4* x4 = reinterpret_cast<const float4*>(x);
  float4 a = x4[2 * t];
  float4 b = x4[2 * t + 1];
  union { unsigned short u[8]; int4 v; } r;
  r.u[0] = f32_to_bf16_rne(a.x); r.u[1] = f32_to_bf16_rne(a.y);
  r.u[2] = f32_to_bf16_rne(a.z); r.u[3] = f32_to_bf16_rne(a.w);
  r.u[4] = f32_to_bf16_rne(b.x); r.u[5] = f32_to_bf16_rne(b.y);
  r.u[6] = f32_to_bf16_rne(b.z); r.u[7] = f32_to_bf16_rne(b.w);
  reinterpret_cast<int4*>(xb)[t] = r.v;
}

// ---------------- Pass 3: 256x256 8-phase bf16 GEMM + bias ----------------
// C[M][N] = A[M][K] * B[N][K]^T + bias. BM=BN=256, BK=64, 8 waves (2Mx4N),
// 512 threads. LDS: A,B each [2buf][256][64] bf16 = 128 KB total.
// Units = tile halves (128 rows x 64 K = 16 KB). Wave frag rows interleave
// halves: row(m) = (m>>2)*128 + wr*64 + (m&3)*16. Phase (qm,qn) reads only
// A-half qm + B-half qn. Stage stream lag ~5 phases; vmcnt(6) checks at P2/P4.
// T2 swizzle: byte ^= ((row&7)<<4); linear LDS dest + pre-swizzled global src.
#define AS1(p) ((const __attribute__((address_space(1))) void*)(p))
#define AS3(p) ((__attribute__((address_space(3))) void*)(p))
#define VM6() asm volatile("s_waitcnt vmcnt(6)" ::: "memory")
#define VM0() asm volatile("s_waitcnt vmcnt(0)" ::: "memory")
#define LGKM0() do { asm volatile("s_waitcnt lgkmcnt(0)" ::: "memory"); \
                     __builtin_amdgcn_sched_barrier(0); } while (0)
#define BAR() __builtin_amdgcn_s_barrier()

__global__ void __launch_bounds__(512, 2) gemm_8phase_kernel(
    const unsigned short* __restrict__ A,  // [GM][GK] bf16 bits
    const unsigned short* __restrict__ B,  // [GN][GK] bf16 bits
    const float* __restrict__ bias, float* __restrict__ C) {
  constexpr int BK = 64, NT = GK / BK;  // 32 K-tiles
  __shared__ __align__(16) unsigned short As[2 * 256 * 64];  // 64 KB
  __shared__ __align__(16) unsigned short Bs[2 * 256 * 64];  // 64 KB

  // XCD swizzle: nwg = 512, divisible by 8 -> bijective simple form
  int bid = blockIdx.x;
  int swz = (bid & 7) * 64 + (bid >> 3);
  int brow = (swz >> 5) * 256;   // 16 M-tiles
  int bcol = (swz & 31) * 256;   // 32 N-tiles

  int tid = threadIdx.x;
  int lane = tid & 63;
  int wave = tid >> 6;
  int wr = wave >> 2;   // 0..1
  int wc = wave & 3;    // 0..3
  int fr = lane & 15;
  int slot = lane >> 4; // 0..3
  int swc = (slot << 4) ^ ((fr & 7) << 4);  // swizzled col-byte base

  const unsigned short* Abase = A + (size_t)brow * GK;
  const unsigned short* Bbase = B + (size_t)bcol * GK;

  // LDS read byte offsets: buf*32768 + qm*16384 + m*2048 + rowbase + (swc ^ (kk<<6))
  int arow = (wr * 64 + fr) * 128;
  int brw = (wc * 32 + fr) * 128;

  f32x4 acc[8][4] = {};
  bf16x8 af[4][2], bf[4][2];

  auto ldA = [&](int buf, int qm, int m, int kk) -> bf16x8 {
    int off = buf * 32768 + qm * 16384 + m * 2048 + arow + (swc ^ (kk << 6));
    return *reinterpret_cast<const bf16x8*>((const char*)As + off);
  };
  auto ldB = [&](int buf, int qn, int n, int kk) -> bf16x8 {
    int off = buf * 32768 + qn * 16384 + n * 2048 + brw + (swc ^ (kk << 6));
    return *reinterpret_cast<const bf16x8*>((const char*)Bs + off);
  };
  // stage half h of tile tt (kt = tt*64) for one matrix; 2 gload_lds/thread.
  auto stageA = [&](int tt) {  // stages half given by caller via h param below
    (void)tt;
  };
  auto stage = [&](const unsigned short* gtile, unsigned short* lds, int buf,
                   int h, int kt) {
#pragma unroll
    for (int i = 0; i < 2; ++i) {
      int L = h * 16384 + i * 8192 + tid * 16;       // linear byte off in tile
      int s = L ^ (((L >> 7) & 7) << 4);             // inverse swizzle -> src
      __builtin_amdgcn_global_load_lds(
          AS1(gtile + (size_t)(s >> 7) * GK + kt + ((s & 127) >> 1)),
          AS3((char*)lds + buf * 32768 + L), 16, 0, 0);
    }
  };

  // Prologue stream: A0(0),B0(0),B1(0),A1(0),A0(1),B0(1)
  stage(Abase, As, 0, 0, 0);
  stage(Bbase, Bs, 0, 0, 0);
  stage(Bbase, Bs, 0, 1, 0);
  stage(Abase, As, 0, 1, 0);
  stage(Abase, As, 1, 0, BK);
  stage(Bbase, Bs, 1, 0, BK);
  VM6();  // A0(0),B0(0),B1(0) landed; A1(0),A0(1),B0(1) in flight
  BAR();

  for (int tt = 0; tt < NT; ++tt) {
    int buf = tt & 1;
    int nbuf = buf ^ 1;
    // ---- P1 (qm0, qn0): 12 ds_reads, stage B1(tt+1) ----
#pragma unroll
    for (int m = 0; m < 4; ++m) {
#pragma unroll
      for (int kk = 0; kk < 2; ++kk) af[m][kk] = ldA(buf, 0, m, kk);
    }
#pragma unroll
    for (int n = 0; n < 2; ++n) {
#pragma unroll
      for (int kk = 0; kk < 2; ++kk) bf[n][kk] = ldB(buf, 0, n, kk);
    }
    if (tt + 1 < NT) stage(Bbase, Bs, nbuf, 1, (tt + 1) * BK);
    BAR();
    LGKM0();
    __builtin_amdgcn_s_setprio(1);
#pragma unroll
    for (int m = 0; m < 4; ++m)
#pragma unroll
      for (int n = 0; n < 2; ++n)
#pragma unroll
        for (int kk = 0; kk < 2; ++kk)
          acc[m][n] = __builtin_amdgcn_mfma_f32_16x16x32_bf16(
              af[m][kk], bf[n][kk], acc[m][n], 0, 0, 0);
    __builtin_amdgcn_s_setprio(0);
    BAR();
    // ---- P2 (qm0, qn1): 4 ds_reads, stage A1(tt+1), MID CHECK ----
#pragma unroll
    for (int n = 2; n < 4; ++n) {
#pragma unroll
      for (int kk = 0; kk < 2; ++kk) bf[n][kk] = ldB(buf, 1, n - 2, kk);
    }
    if (tt + 1 < NT) stage(Abase, As, nbuf, 1, (tt + 1) * BK);
    if (tt >= NT - 2) { VM0(); } else { VM6(); }  // protects P3's A1(tt)
    BAR();
    LGKM0();
    __builtin_amdgcn_s_setprio(1);
#pragma unroll
    for (int m = 0; m < 4; ++m)
#pragma unroll
      for (int n = 2; n < 4; ++n)
#pragma unroll
        for (int kk = 0; kk < 2; ++kk)
          acc[m][n] = __builtin_amdgcn_mfma_f32_16x16x32_bf16(
              af[m][kk], bf[n][kk], acc[m][n], 0, 0, 0);
    __builtin_amdgcn_s_setprio(0);
    BAR();
    // ---- P3 (qm1, qn0): 8 ds_reads, stage A0(tt+2) ----
#pragma unroll
    for (int m = 0; m < 4; ++m) {
#pragma unroll
      for (int kk = 0; kk < 2; ++kk) af[m][kk] = ldA(buf, 1, m, kk);
    }
    if (tt + 2 < NT) stage(Abase, As, buf, 0, (tt + 2) * BK);
    BAR();
    LGKM0();
    __builtin_amdgcn_s_setprio(1);
#pragma unroll
    for (int m = 0; m < 4; ++m)
#pragma unroll
      for (int n = 0; n < 2; ++n)
#pragma unroll
        for (int kk = 0; kk < 2; ++kk)
          acc[4 + m][n] = __builtin_amdgcn_mfma_f32_16x16x32_bf16(
              af[m][kk], bf[n][kk], acc[4 + m][n], 0, 0, 0);
    __builtin_amdgcn_s_setprio(0);
    BAR();
    // ---- P4 (qm1, qn1): 0 ds_reads, stage B0(tt+2), BOUNDARY CHECK ----
    if (tt + 2 < NT) stage(Bbase, Bs, buf, 0, (tt + 2) * BK);
    if (tt + 1 >= NT - 2) { VM0(); } else { VM6(); }  // protects tile tt+1
    BAR();
    __builtin_amdgcn_s_setprio(1);
#pragma unroll
    for (int m = 0; m < 4; ++m)
#pragma unroll
      for (int n = 2; n < 4; ++n)
#pragma unroll
        for (int kk = 0; kk < 2; ++kk)
          acc[4 + m][n] = __builtin_amdgcn_mfma_f32_16x16x32_bf16(
              af[m][kk], bf[n][kk], acc[4 + m][n], 0, 0, 0);
    __builtin_amdgcn_s_setprio(0);
    BAR();
  }

  // Epilogue: C/D frag layout col=fr, row=slot*4+reg [m89/m91]
  float bv[4];
#pragma unroll
  for (int n = 0; n < 4; ++n)
    bv[n] = bias[bcol + (n >> 1) * 128 + wc * 32 + (n & 1) * 16 + fr];
#pragma unroll
  for (int m = 0; m < 8; ++m) {
    int grow0 = brow + (m >> 2) * 128 + wr * 64 + (m & 3) * 16 + slot * 4;
#pragma unroll
    for (int n = 0; n < 4; ++n) {
      int gcol = bcol + (n >> 1) * 128 + wc * 32 + (n & 1) * 16 + fr;
#pragma unroll
      for (int r = 0; r < 4; ++r)
        C[(size_t)(grow0 + r) * GN + gcol] = acc[m][n][r] + bv[n];
    }
  }
}

// ---------------- Fallback (ws too small): fp32, correct, slow ----------------
__global__ void __launch_bounds__(256) fallback_kernel(
    const float* __restrict__ x, const int* __restrict__ q,
    const float* __restrict__ scale, const float* __restrict__ bias,
    float* __restrict__ out) {
  __shared__ float wrow[GK];
  int n = blockIdx.x;
  for (int k = threadIdx.x; k < GK; k += 256) {
    size_t idx = (size_t)n * GK + k;
    wrow[k] = NF4_LUT[q[idx] & 15] * scale[idx >> 6];
  }
  __syncthreads();
  int m = blockIdx.y * 256 + threadIdx.x;
  const float* xr = x + (size_t)m * GK;
  float acc = 0.f;
  for (int k = 0; k < GK; ++k) acc += xr[k] * wrow[k];
  out[(size_t)m * GN + n] = acc + bias[n];
}

extern "C" void kernel_launch(void* const* d_in, const int* in_sizes, int n_in,
                              void* d_out, int out_size, void* d_ws, size_t ws_size,
                              hipStream_t stream) {
  const float* x = (const float*)d_in[0];
  const int* q = (const int*)d_in[1];
  const float* scale = (const float*)d_in[2];
  const float* bias = (const float*)d_in[3];
  float* out = (float*)d_out;

  const size_t wbytes = (size_t)GN * GK * 2;
  const size_t xbytes = (size_t)GM * GK * 2;

  if (ws_size >= wbytes + xbytes) {
    unsigned short* wq = (unsigned short*)d_ws;
    unsigned short* xb = (unsigned short*)((char*)d_ws + wbytes);
    dequant_nf4_kernel<<<(GN * GK / 8) / 256, 256, 0, stream>>>(q, scale, wq);
    cvt_f32_bf16_kernel<<<(GM * GK / 8) / 256, 256, 0, stream>>>(x, xb);
    gemm_8phase_kernel<<<dim3((GM / 256) * (GN / 256)), 512, 0, stream>>>(
        xb, wq, bias, out);
  } else {
    fallback_kernel<<<dim3(GN, GM / 256), 256, 0, stream>>>(x, q, scale, bias, out);
  }
}

// Round 3
// 155.705 us; speedup vs baseline: 1.3579x; 1.0772x over previous
//
#include <hip/hip_runtime.h>
#include <stdint.h>

#define GM 4096   // 2*2048 rows of x
#define GN 8192   // out_features
#define GK 2048   // in_features

typedef float f32x4 __attribute__((ext_vector_type(4)));
typedef __bf16 bf16x8 __attribute__((ext_vector_type(8)));

__device__ __constant__ float NF4_LUT[16] = {
    -1.0f, -0.6961928009986877f, -0.5250730514526367f, -0.39491748809814453f,
    -0.28444138169288635f, -0.18477343022823334f, -0.09105003625154495f, 0.0f,
    0.07958029955625534f, 0.16093020141124725f, 0.24611230194568634f,
    0.33791524171829224f, 0.44070982933044434f, 0.5626170039176941f,
    0.7229568362236023f, 1.0f};

__device__ __forceinline__ unsigned short f32_to_bf16_rne(float f) {
  union { float f; uint32_t u; } v;
  v.f = f;
  uint32_t lsb = (v.u >> 16) & 1u;
  v.u += 0x7fffu + lsb;
  return (unsigned short)(v.u >> 16);
}

// ---------------- Pass 1: NF4 dequant -> bf16 W [GN][GK] ----------------
__global__ void __launch_bounds__(256) dequant_nf4_kernel(
    const int* __restrict__ q, const float* __restrict__ scale,
    unsigned short* __restrict__ w) {
  __shared__ float lut[16];
  if (threadIdx.x < 16) lut[threadIdx.x] = NF4_LUT[threadIdx.x];
  __syncthreads();
  int t = blockIdx.x * 256 + threadIdx.x;
  const int4* q4 = reinterpret_cast<const int4*>(q);
  int4 c0 = q4[2 * t];
  int4 c1 = q4[2 * t + 1];
  float s = scale[t >> 3];
  int codes[8] = {c0.x, c0.y, c0.z, c0.w, c1.x, c1.y, c1.z, c1.w};
  union { unsigned short u[8]; int4 v; } r;
#pragma unroll
  for (int j = 0; j < 8; ++j)
    r.u[j] = f32_to_bf16_rne(lut[codes[j] & 15] * s);
  reinterpret_cast<int4*>(w)[t] = r.v;
}

// ---------------- Pass 2: x fp32 -> bf16 [GM][GK] ----------------
__global__ void __launch_bounds__(256) cvt_f32_bf16_kernel(
    const float* __restrict__ x, unsigned short* __restrict__ xb) {
  int t = blockIdx.x * 256 + threadIdx.x;
  const float4* x4 = reinterpret_cast<const float4*>(x);
  float4 a = x4[2 * t];
  float4 b = x4[2 * t + 1];
  union { unsigned short u[8]; int4 v; } r;
  r.u[0] = f32_to_bf16_rne(a.x); r.u[1] = f32_to_bf16_rne(a.y);
  r.u[2] = f32_to_bf16_rne(a.z); r.u[3] = f32_to_bf16_rne(a.w);
  r.u[4] = f32_to_bf16_rne(b.x); r.u[5] = f32_to_bf16_rne(b.y);
  r.u[6] = f32_to_bf16_rne(b.z); r.u[7] = f32_to_bf16_rne(b.w);
  reinterpret_cast<int4*>(xb)[t] = r.v;
}

// ---------------- Pass 3: 256x256 8-phase pipelined bf16 GEMM + bias ------
// BM=BN=256, BK=64, 8 waves (2Mx4N), 512 threads, LDS 128KB (2 static bufs:
// even tiles -> buf0, odd -> buf1). Snake quadrants Q1..Q4 per tile; frag
// ds_reads issued ONE PHASE before their MFMA (compiler emits counted
// lgkmcnt). Stages: P1:B1(O), P3:A0+B0(E+2), P4:A1(E+2), P5:B1(E+2),
// P7:A0+B0(O+2), P8:A1(O+2); vmcnt(6) checks at P4/P8 only.
// T2 swizzle: byte ^= ((row&7)<<4), linear LDS dest + pre-swizzled gsrc.
#define AS1(p) ((const __attribute__((address_space(1))) void*)(p))
#define AS3(p) ((__attribute__((address_space(3))) void*)(p))
#define VM6() asm volatile("s_waitcnt vmcnt(6)" ::: "memory")
#define FENCE() asm volatile("" ::: "memory")
#define BAR() do { FENCE(); __builtin_amdgcn_s_barrier(); FENCE(); } while (0)

__global__ void __launch_bounds__(512, 2) gemm_8phase_kernel(
    const unsigned short* __restrict__ A,  // [GM][GK] bf16 bits
    const unsigned short* __restrict__ B,  // [GN][GK] bf16 bits
    const float* __restrict__ bias, float* __restrict__ C) {
  constexpr int BK = 64, NT = GK / BK;  // 32 K-tiles, 16 iters x 2 tiles
  __shared__ __align__(16) unsigned short As[2 * 256 * 64];  // 64 KB
  __shared__ __align__(16) unsigned short Bs[2 * 256 * 64];  // 64 KB

  int bid = blockIdx.x;
  int swz = (bid & 7) * 64 + (bid >> 3);  // nwg=512, bijective
  int brow = (swz >> 5) * 256;
  int bcol = (swz & 31) * 256;

  int tid = threadIdx.x;
  int lane = tid & 63;
  int wave = tid >> 6;
  int wr = wave >> 2;   // 0..1
  int wc = wave & 3;    // 0..3
  int fr = lane & 15;
  int slot = lane >> 4;
  int swc = (slot << 4) ^ ((fr & 7) << 4);

  const unsigned short* Abase = A + (size_t)brow * GK;
  const unsigned short* Bbase = B + (size_t)bcol * GK;

  int arow = (wr * 64 + fr) * 128;
  int brw = (wc * 32 + fr) * 128;

  f32x4 acc[8][4] = {};
  // frag regs: [parity][frag][kk]; parity 0 = even tile (buf0), 1 = odd.
  bf16x8 a0[2][4][2], a1[2][4][2], b0[2][2][2], b1[2][2][2];

  auto ldA = [&](int buf, int qm, int m, int kk) -> bf16x8 {
    int off = buf * 32768 + qm * 16384 + m * 2048 + arow + (swc ^ (kk << 6));
    return *reinterpret_cast<const bf16x8*>((const char*)As + off);
  };
  auto ldB = [&](int buf, int qn, int n, int kk) -> bf16x8 {
    int off = buf * 32768 + qn * 16384 + n * 2048 + brw + (swc ^ (kk << 6));
    return *reinterpret_cast<const bf16x8*>((const char*)Bs + off);
  };
  auto stage = [&](const unsigned short* gtile, unsigned short* lds, int buf,
                   int h, int kt) {
#pragma unroll
    for (int i = 0; i < 2; ++i) {
      int L = h * 16384 + i * 8192 + tid * 16;
      int s = L ^ (((L >> 7) & 7) << 4);
      __builtin_amdgcn_global_load_lds(
          AS1(gtile + (size_t)(s >> 7) * GK + kt + ((s & 127) >> 1)),
          AS3((char*)lds + buf * 32768 + L), 16, 0, 0);
    }
  };
  // read groups (issued one phase ahead of consumption)
  auto RD_A1 = [&](int p) {  // 8 reads
#pragma unroll
    for (int m = 0; m < 4; ++m)
#pragma unroll
      for (int kk = 0; kk < 2; ++kk) a1[p][m][kk] = ldA(p, 1, m, kk);
  };
  auto RD_B1 = [&](int p) {  // 4 reads
#pragma unroll
    for (int n = 0; n < 2; ++n)
#pragma unroll
      for (int kk = 0; kk < 2; ++kk) b1[p][n][kk] = ldB(p, 1, n, kk);
  };
  auto RD_A0B0 = [&](int p) {  // 12 reads
#pragma unroll
    for (int m = 0; m < 4; ++m)
#pragma unroll
      for (int kk = 0; kk < 2; ++kk) a0[p][m][kk] = ldA(p, 0, m, kk);
#pragma unroll
    for (int n = 0; n < 2; ++n)
#pragma unroll
      for (int kk = 0; kk < 2; ++kk) b0[p][n][kk] = ldB(p, 0, n, kk);
  };
  auto Q1 = [&](int p) {  // m0-3 x n0-1 : a0 x b0
    __builtin_amdgcn_s_setprio(1);
#pragma unroll
    for (int m = 0; m < 4; ++m)
#pragma unroll
      for (int n = 0; n < 2; ++n)
#pragma unroll
        for (int kk = 0; kk < 2; ++kk)
          acc[m][n] = __builtin_amdgcn_mfma_f32_16x16x32_bf16(
              a0[p][m][kk], b0[p][n][kk], acc[m][n], 0, 0, 0);
    __builtin_amdgcn_s_setprio(0);
  };
  auto Q2 = [&](int p) {  // m4-7 x n0-1 : a1 x b0
    __builtin_amdgcn_s_setprio(1);
#pragma unroll
    for (int m = 0; m < 4; ++m)
#pragma unroll
      for (int n = 0; n < 2; ++n)
#pragma unroll
        for (int kk = 0; kk < 2; ++kk)
          acc[4 + m][n] = __builtin_amdgcn_mfma_f32_16x16x32_bf16(
              a1[p][m][kk], b0[p][n][kk], acc[4 + m][n], 0, 0, 0);
    __builtin_amdgcn_s_setprio(0);
  };
  auto Q3 = [&](int p) {  // m4-7 x n2-3 : a1 x b1
    __builtin_amdgcn_s_setprio(1);
#pragma unroll
    for (int m = 0; m < 4; ++m)
#pragma unroll
      for (int n = 0; n < 2; ++n)
#pragma unroll
        for (int kk = 0; kk < 2; ++kk)
          acc[4 + m][2 + n] = __builtin_amdgcn_mfma_f32_16x16x32_bf16(
              a1[p][m][kk], b1[p][n][kk], acc[4 + m][2 + n], 0, 0, 0);
    __builtin_amdgcn_s_setprio(0);
  };
  auto Q4 = [&](int p) {  // m0-3 x n2-3 : a0 x b1
    __builtin_amdgcn_s_setprio(1);
#pragma unroll
    for (int m = 0; m < 4; ++m)
#pragma unroll
      for (int n = 0; n < 2; ++n)
#pragma unroll
        for (int kk = 0; kk < 2; ++kk)
          acc[m][2 + n] = __builtin_amdgcn_mfma_f32_16x16x32_bf16(
              a0[p][m][kk], b1[p][n][kk], acc[m][2 + n], 0, 0, 0);
    __builtin_amdgcn_s_setprio(0);
  };

  // Prologue: stage tile0 fully + tile1 {A0,B0,A1}; vmcnt(6) -> tile0 landed.
  stage(Abase, As, 0, 0, 0);
  stage(Bbase, Bs, 0, 0, 0);
  stage(Abase, As, 0, 1, 0);
  stage(Bbase, Bs, 0, 1, 0);
  stage(Abase, As, 1, 0, BK);
  stage(Bbase, Bs, 1, 0, BK);
  stage(Abase, As, 1, 1, BK);
  VM6();
  BAR();
  RD_A0B0(0);  // tile0 a0,b0 -> feeds P1's Q1

#pragma unroll 1
  for (int j = 0; j < NT / 2; ++j) {
    int t1 = 2 * j + 1;
    int t2 = (2 * j + 2 < NT) ? 2 * j + 2 : NT - 1;  // clamp: tail re-stages
    int t3 = (2 * j + 3 < NT) ? 2 * j + 3 : NT - 1;  // tile31 (dead regions)
    int kt1 = t1 * BK, kt2 = t2 * BK, kt3 = t3 * BK;
    // P1
    RD_A1(0);
    stage(Bbase, Bs, 1, 1, kt1);   // B1(O)
    BAR();
    Q1(0);
    // P2
    RD_B1(0);
    BAR();
    Q2(0);
    // P3
    stage(Abase, As, 0, 0, kt2);   // A0(E+2)
    stage(Bbase, Bs, 0, 0, kt2);   // B0(E+2)
    BAR();
    Q3(0);
    // P4
    stage(Abase, As, 0, 1, kt2);   // A1(E+2)
    VM6();                         // -> B1(O) + older landed
    BAR();
    RD_A0B0(1);                    // tile O a0,b0 -> feeds P5
    Q4(0);
    // P5
    RD_A1(1);
    stage(Bbase, Bs, 0, 1, kt2);   // B1(E+2)
    BAR();
    Q1(1);
    // P6
    RD_B1(1);
    BAR();
    Q2(1);
    // P7
    stage(Abase, As, 1, 0, kt3);   // A0(O+2)
    stage(Bbase, Bs, 1, 0, kt3);   // B0(O+2)
    BAR();
    Q3(1);
    // P8
    stage(Abase, As, 1, 1, kt3);   // A1(O+2)
    VM6();                         // -> B1(E+2) + older landed
    BAR();
    RD_A0B0(0);                    // tile E+2 a0,b0 -> feeds next P1
    Q4(1);
  }

  // Epilogue: C/D frag layout col=fr, row=slot*4+reg [m89/m91]
  float bv[4];
#pragma unroll
  for (int n = 0; n < 4; ++n)
    bv[n] = bias[bcol + (n >> 1) * 128 + wc * 32 + (n & 1) * 16 + fr];
#pragma unroll
  for (int m = 0; m < 8; ++m) {
    int grow0 = brow + (m >> 2) * 128 + wr * 64 + (m & 3) * 16 + slot * 4;
#pragma unroll
    for (int n = 0; n < 4; ++n) {
      int gcol = bcol + (n >> 1) * 128 + wc * 32 + (n & 1) * 16 + fr;
#pragma unroll
      for (int r = 0; r < 4; ++r)
        C[(size_t)(grow0 + r) * GN + gcol] = acc[m][n][r] + bv[n];
    }
  }
}

// ---------------- Fallback (ws too small): fp32, correct, slow ----------------
__global__ void __launch_bounds__(256) fallback_kernel(
    const float* __restrict__ x, const int* __restrict__ q,
    const float* __restrict__ scale, const float* __restrict__ bias,
    float* __restrict__ out) {
  __shared__ float wrow[GK];
  int n = blockIdx.x;
  for (int k = threadIdx.x; k < GK; k += 256) {
    size_t idx = (size_t)n * GK + k;
    wrow[k] = NF4_LUT[q[idx] & 15] * scale[idx >> 6];
  }
  __syncthreads();
  int m = blockIdx.y * 256 + threadIdx.x;
  const float* xr = x + (size_t)m * GK;
  float acc = 0.f;
  for (int k = 0; k < GK; ++k) acc += xr[k] * wrow[k];
  out[(size_t)m * GN + n] = acc + bias[n];
}

extern "C" void kernel_launch(void* const* d_in, const int* in_sizes, int n_in,
                              void* d_out, int out_size, void* d_ws, size_t ws_size,
                              hipStream_t stream) {
  const float* x = (const float*)d_in[0];
  const int* q = (const int*)d_in[1];
  const float* scale = (const float*)d_in[2];
  const float* bias = (const float*)d_in[3];
  float* out = (float*)d_out;

  const size_t wbytes = (size_t)GN * GK * 2;
  const size_t xbytes = (size_t)GM * GK * 2;

  if (ws_size >= wbytes + xbytes) {
    unsigned short* wq = (unsigned short*)d_ws;
    unsigned short* xb = (unsigned short*)((char*)d_ws + wbytes);
    dequant_nf4_kernel<<<(GN * GK / 8) / 256, 256, 0, stream>>>(q, scale, wq);
    cvt_f32_bf16_kernel<<<(GM * GK / 8) / 256, 256, 0, stream>>>(x, xb);
    gemm_8phase_kernel<<<dim3((GM / 256) * (GN / 256)), 512, 0, stream>>>(
        xb, wq, bias, out);
  } else {
    fallback_kernel<<<dim3(GN, GM / 256), 256, 0, stream>>>(x, q, scale, bias, out);
  }
}

// Round 4
// 154.181 us; speedup vs baseline: 1.3713x; 1.0099x over previous
//
#include <hip/hip_runtime.h>
#include <stdint.h>

#define GM 4096   // 2*2048 rows of x
#define GN 8192   // out_features
#define GK 2048   // in_features

typedef float f32x4 __attribute__((ext_vector_type(4)));
typedef __bf16 bf16x8 __attribute__((ext_vector_type(8)));

__device__ __constant__ float NF4_LUT[16] = {
    -1.0f, -0.6961928009986877f, -0.5250730514526367f, -0.39491748809814453f,
    -0.28444138169288635f, -0.18477343022823334f, -0.09105003625154495f, 0.0f,
    0.07958029955625534f, 0.16093020141124725f, 0.24611230194568634f,
    0.33791524171829224f, 0.44070982933044434f, 0.5626170039176941f,
    0.7229568362236023f, 1.0f};

__device__ __forceinline__ unsigned short f32_to_bf16_rne(float f) {
  union { float f; uint32_t u; } v;
  v.f = f;
  uint32_t lsb = (v.u >> 16) & 1u;
  v.u += 0x7fffu + lsb;
  return (unsigned short)(v.u >> 16);
}

// ---------------- Pass 1: NF4 dequant -> bf16 W [GN][GK] ----------------
__global__ void __launch_bounds__(256) dequant_nf4_kernel(
    const int* __restrict__ q, const float* __restrict__ scale,
    unsigned short* __restrict__ w) {
  __shared__ float lut[16];
  if (threadIdx.x < 16) lut[threadIdx.x] = NF4_LUT[threadIdx.x];
  __syncthreads();
  int t = blockIdx.x * 256 + threadIdx.x;
  const int4* q4 = reinterpret_cast<const int4*>(q);
  int4 c0 = q4[2 * t];
  int4 c1 = q4[2 * t + 1];
  float s = scale[t >> 3];
  int codes[8] = {c0.x, c0.y, c0.z, c0.w, c1.x, c1.y, c1.z, c1.w};
  union { unsigned short u[8]; int4 v; } r;
#pragma unroll
  for (int j = 0; j < 8; ++j)
    r.u[j] = f32_to_bf16_rne(lut[codes[j] & 15] * s);
  reinterpret_cast<int4*>(w)[t] = r.v;
}

// ---------------- Pass 2: x fp32 -> bf16 [GM][GK] ----------------
__global__ void __launch_bounds__(256) cvt_f32_bf16_kernel(
    const float* __restrict__ x, unsigned short* __restrict__ xb) {
  int t = blockIdx.x * 256 + threadIdx.x;
  const float4* x4 = reinterpret_cast<const float4*>(x);
  float4 a = x4[2 * t];
  float4 b = x4[2 * t + 1];
  union { unsigned short u[8]; int4 v; } r;
  r.u[0] = f32_to_bf16_rne(a.x); r.u[1] = f32_to_bf16_rne(a.y);
  r.u[2] = f32_to_bf16_rne(a.z); r.u[3] = f32_to_bf16_rne(a.w);
  r.u[4] = f32_to_bf16_rne(b.x); r.u[5] = f32_to_bf16_rne(b.y);
  r.u[6] = f32_to_bf16_rne(b.z); r.u[7] = f32_to_bf16_rne(b.w);
  reinterpret_cast<int4*>(xb)[t] = r.v;
}

// ------ Pass 3: persistent 256x256 8-phase GEMM, 2 output tiles/block ------
// Grid 256 = 1 block/CU. Each block: brow fixed, bcol pair (p*512, p*512+256);
// 64 virtual K-tiles (A repeats, B pointer switches at v=32). Seamless stage
// stream across the boundary; tile-1 epilogue = fire-and-forget mid-flush
// whose store BW hides under tile-2's K-loop. Ledger identical to R3.
// XCD remap: B pair-panels XCD-affine (B fetched ~1x/XCD, A ~8x).
#define AS1(p) ((const __attribute__((address_space(1))) void*)(p))
#define AS3(p) ((__attribute__((address_space(3))) void*)(p))
#define VM6() asm volatile("s_waitcnt vmcnt(6)" ::: "memory")
#define FENCE() asm volatile("" ::: "memory")
#define BAR() do { FENCE(); __builtin_amdgcn_s_barrier(); FENCE(); } while (0)

__global__ void __launch_bounds__(512, 1) gemm_8phase_kernel(
    const unsigned short* __restrict__ A,  // [GM][GK] bf16 bits
    const unsigned short* __restrict__ B,  // [GN][GK] bf16 bits
    const float* __restrict__ bias, float* __restrict__ C) {
  constexpr int BK = 64;
  constexpr int NV = 64;  // virtual K-tiles: 2 output tiles x 32
  __shared__ __align__(16) unsigned short As[2 * 256 * 64];  // 64 KB
  __shared__ __align__(16) unsigned short Bs[2 * 256 * 64];  // 64 KB

  int bid = blockIdx.x;                    // nwg = 256, %8==0 -> bijective
  int swz = (bid & 7) * 32 + (bid >> 3);
  int brow = (swz & 15) * 256;             // A panel varies within XCD
  int pair = swz >> 4;                     // B pair-panel is XCD-affine
  int bcol0 = pair * 512;

  int tid = threadIdx.x;
  int lane = tid & 63;
  int wave = tid >> 6;
  int wr = wave >> 2;   // 0..1
  int wc = wave & 3;    // 0..3
  int fr = lane & 15;
  int slot = lane >> 4;
  int swc = (slot << 4) ^ ((fr & 7) << 4);

  const unsigned short* Abase = A + (size_t)brow * GK;
  const unsigned short* Bbase0 = B + (size_t)bcol0 * GK;
  const unsigned short* Bbase1 = Bbase0 + (size_t)256 * GK;

  int arow = (wr * 64 + fr) * 128;
  int brw = (wc * 32 + fr) * 128;

  f32x4 acc[8][4] = {};
  bf16x8 a0[2][4][2], a1[2][4][2], b0[2][2][2], b1[2][2][2];

  auto ldA = [&](int buf, int qm, int m, int kk) -> bf16x8 {
    int off = buf * 32768 + qm * 16384 + m * 2048 + arow + (swc ^ (kk << 6));
    return *reinterpret_cast<const bf16x8*>((const char*)As + off);
  };
  auto ldB = [&](int buf, int qn, int n, int kk) -> bf16x8 {
    int off = buf * 32768 + qn * 16384 + n * 2048 + brw + (swc ^ (kk << 6));
    return *reinterpret_cast<const bf16x8*>((const char*)Bs + off);
  };
  auto stage = [&](const unsigned short* gtile, unsigned short* lds, int buf,
                   int h, int kt) {
#pragma unroll
    for (int i = 0; i < 2; ++i) {
      int L = h * 16384 + i * 8192 + tid * 16;
      int s = L ^ (((L >> 7) & 7) << 4);
      __builtin_amdgcn_global_load_lds(
          AS1(gtile + (size_t)(s >> 7) * GK + kt + ((s & 127) >> 1)),
          AS3((char*)lds + buf * 32768 + L), 16, 0, 0);
    }
  };
  auto RD_A1 = [&](int p) {
#pragma unroll
    for (int m = 0; m < 4; ++m)
#pragma unroll
      for (int kk = 0; kk < 2; ++kk) a1[p][m][kk] = ldA(p, 1, m, kk);
  };
  auto RD_B1 = [&](int p) {
#pragma unroll
    for (int n = 0; n < 2; ++n)
#pragma unroll
      for (int kk = 0; kk < 2; ++kk) b1[p][n][kk] = ldB(p, 1, n, kk);
  };
  auto RD_A0B0 = [&](int p) {
#pragma unroll
    for (int m = 0; m < 4; ++m)
#pragma unroll
      for (int kk = 0; kk < 2; ++kk) a0[p][m][kk] = ldA(p, 0, m, kk);
#pragma unroll
    for (int n = 0; n < 2; ++n)
#pragma unroll
      for (int kk = 0; kk < 2; ++kk) b0[p][n][kk] = ldB(p, 0, n, kk);
  };
  auto Q1 = [&](int p) {
    __builtin_amdgcn_s_setprio(1);
#pragma unroll
    for (int m = 0; m < 4; ++m)
#pragma unroll
      for (int n = 0; n < 2; ++n)
#pragma unroll
        for (int kk = 0; kk < 2; ++kk)
          acc[m][n] = __builtin_amdgcn_mfma_f32_16x16x32_bf16(
              a0[p][m][kk], b0[p][n][kk], acc[m][n], 0, 0, 0);
    __builtin_amdgcn_s_setprio(0);
  };
  auto Q2 = [&](int p) {
    __builtin_amdgcn_s_setprio(1);
#pragma unroll
    for (int m = 0; m < 4; ++m)
#pragma unroll
      for (int n = 0; n < 2; ++n)
#pragma unroll
        for (int kk = 0; kk < 2; ++kk)
          acc[4 + m][n] = __builtin_amdgcn_mfma_f32_16x16x32_bf16(
              a1[p][m][kk], b0[p][n][kk], acc[4 + m][n], 0, 0, 0);
    __builtin_amdgcn_s_setprio(0);
  };
  auto Q3 = [&](int p) {
    __builtin_amdgcn_s_setprio(1);
#pragma unroll
    for (int m = 0; m < 4; ++m)
#pragma unroll
      for (int n = 0; n < 2; ++n)
#pragma unroll
        for (int kk = 0; kk < 2; ++kk)
          acc[4 + m][2 + n] = __builtin_amdgcn_mfma_f32_16x16x32_bf16(
              a1[p][m][kk], b1[p][n][kk], acc[4 + m][2 + n], 0, 0, 0);
    __builtin_amdgcn_s_setprio(0);
  };
  auto Q4 = [&](int p) {
    __builtin_amdgcn_s_setprio(1);
#pragma unroll
    for (int m = 0; m < 4; ++m)
#pragma unroll
      for (int n = 0; n < 2; ++n)
#pragma unroll
        for (int kk = 0; kk < 2; ++kk)
          acc[m][2 + n] = __builtin_amdgcn_mfma_f32_16x16x32_bf16(
              a0[p][m][kk], b1[p][n][kk], acc[m][2 + n], 0, 0, 0);
    __builtin_amdgcn_s_setprio(0);
  };
  auto flush = [&](int bc) {
    float bv[4];
#pragma unroll
    for (int n = 0; n < 4; ++n)
      bv[n] = bias[bc + (n >> 1) * 128 + wc * 32 + (n & 1) * 16 + fr];
#pragma unroll
    for (int m = 0; m < 8; ++m) {
      int grow0 = brow + (m >> 2) * 128 + wr * 64 + (m & 3) * 16 + slot * 4;
#pragma unroll
      for (int n = 0; n < 4; ++n) {
        int gcol = bc + (n >> 1) * 128 + wc * 32 + (n & 1) * 16 + fr;
#pragma unroll
        for (int r = 0; r < 4; ++r)
          C[(size_t)(grow0 + r) * GN + gcol] = acc[m][n][r] + bv[n];
      }
    }
  };
  // one pipelined double-tile iteration over virtual tiles v=2j, 2j+1
  auto iter = [&](int j) {
    int t1 = 2 * j + 1;
    int t2 = 2 * j + 2; if (t2 > NV - 1) t2 = NV - 1;  // tail dummy restage
    int t3 = 2 * j + 3; if (t3 > NV - 1) t3 = NV - 1;
    const unsigned short* B1p = (t1 < 32) ? Bbase0 : Bbase1;
    const unsigned short* B2p = (t2 < 32) ? Bbase0 : Bbase1;
    const unsigned short* B3p = (t3 < 32) ? Bbase0 : Bbase1;
    int kt1 = (t1 & 31) * BK, kt2 = (t2 & 31) * BK, kt3 = (t3 & 31) * BK;
    // P1
    RD_A1(0);
    stage(B1p, Bs, 1, 1, kt1);
    BAR();
    Q1(0);
    // P2
    RD_B1(0);
    BAR();
    Q2(0);
    // P3
    stage(Abase, As, 0, 0, kt2);
    stage(B2p, Bs, 0, 0, kt2);
    BAR();
    Q3(0);
    // P4
    stage(Abase, As, 0, 1, kt2);
    VM6();
    BAR();
    RD_A0B0(1);
    Q4(0);
    // P5
    RD_A1(1);
    stage(B2p, Bs, 0, 1, kt2);
    BAR();
    Q1(1);
    // P6
    RD_B1(1);
    BAR();
    Q2(1);
    // P7
    stage(Abase, As, 1, 0, kt3);
    stage(B3p, Bs, 1, 0, kt3);
    BAR();
    Q3(1);
    // P8
    stage(Abase, As, 1, 1, kt3);
    VM6();
    BAR();
    RD_A0B0(0);
    Q4(1);
  };

  // Prologue: stage v0 fully + v1 {A0,B0,A1}
  stage(Abase, As, 0, 0, 0);
  stage(Bbase0, Bs, 0, 0, 0);
  stage(Abase, As, 0, 1, 0);
  stage(Bbase0, Bs, 0, 1, 0);
  stage(Abase, As, 1, 0, BK);
  stage(Bbase0, Bs, 1, 0, BK);
  stage(Abase, As, 1, 1, BK);
  VM6();
  BAR();
  RD_A0B0(0);

#pragma unroll 1
  for (int j = 0; j < 16; ++j) iter(j);

  // mid-flush: tile-1 stores fly while tile-2's K-loop runs
  flush(bcol0);
#pragma unroll
  for (int m = 0; m < 8; ++m)
#pragma unroll
    for (int n = 0; n < 4; ++n)
      acc[m][n] = f32x4{0.f, 0.f, 0.f, 0.f};

#pragma unroll 1
  for (int j = 16; j < 32; ++j) iter(j);

  flush(bcol0 + 256);
}

// ---------------- Fallback (ws too small): fp32, correct, slow ----------------
__global__ void __launch_bounds__(256) fallback_kernel(
    const float* __restrict__ x, const int* __restrict__ q,
    const float* __restrict__ scale, const float* __restrict__ bias,
    float* __restrict__ out) {
  __shared__ float wrow[GK];
  int n = blockIdx.x;
  for (int k = threadIdx.x; k < GK; k += 256) {
    size_t idx = (size_t)n * GK + k;
    wrow[k] = NF4_LUT[q[idx] & 15] * scale[idx >> 6];
  }
  __syncthreads();
  int m = blockIdx.y * 256 + threadIdx.x;
  const float* xr = x + (size_t)m * GK;
  float acc = 0.f;
  for (int k = 0; k < GK; ++k) acc += xr[k] * wrow[k];
  out[(size_t)m * GN + n] = acc + bias[n];
}

extern "C" void kernel_launch(void* const* d_in, const int* in_sizes, int n_in,
                              void* d_out, int out_size, void* d_ws, size_t ws_size,
                              hipStream_t stream) {
  const float* x = (const float*)d_in[0];
  const int* q = (const int*)d_in[1];
  const float* scale = (const float*)d_in[2];
  const float* bias = (const float*)d_in[3];
  float* out = (float*)d_out;

  const size_t wbytes = (size_t)GN * GK * 2;
  const size_t xbytes = (size_t)GM * GK * 2;

  if (ws_size >= wbytes + xbytes) {
    unsigned short* wq = (unsigned short*)d_ws;
    unsigned short* xb = (unsigned short*)((char*)d_ws + wbytes);
    dequant_nf4_kernel<<<(GN * GK / 8) / 256, 256, 0, stream>>>(q, scale, wq);
    cvt_f32_bf16_kernel<<<(GM * GK / 8) / 256, 256, 0, stream>>>(x, xb);
    gemm_8phase_kernel<<<dim3(256), 512, 0, stream>>>(xb, wq, bias, out);
  } else {
    fallback_kernel<<<dim3(GN, GM / 256), 256, 0, stream>>>(x, q, scale, bias, out);
  }
}